// Round 8
// baseline (308.175 us; speedup 1.0000x reference)
//
#include <hip/hip_runtime.h>
#include <stdint.h>
#include <stddef.h>

typedef unsigned int u32;
typedef unsigned long long u64;

#define NB 4
#define NLEV 5
#define NCH 72      // A*C = 9*8
#define NREGCH 36   // A*4
#define TOPK 1000
#define NCAND 5000  // NLEV*TOPK
#define NDET 300
#define NBINS 16384       // fallback hist: sigmoid float bits >> 16
#define CAP 8192          // per-(b,level) filtered-candidate buffer
#define CHUNK 8192
#define NCHUNK_IMG 50     // 36+9+3+1+1
#define IMGSZ 512.0f
#define SCORE_TH 0.05f
#define NMS_TH 0.5f
#define BBOX_CLIP_F 4.135166556742356f

__constant__ int c_f[NLEV]    = {64, 32, 16, 8, 4};
__constant__ int c_Nloc[NLEV] = {4096, 1024, 256, 64, 16};
__constant__ int c_lg2[NLEV]  = {12, 10, 8, 6, 4};
// logit prefilter thresholds: ~1770 expected survivors at levels 0-3; level 4 unfiltered.
__constant__ float c_tau[NLEV] = {2.512f, 1.977f, 1.305f, 0.295f, -1e30f};

// ---- XLA-CPU-style sigmoid: logistic(x) = 0.5 + 0.5*tanh(0.5*x), fast-tanh poly, no FMA ----
__device__ __forceinline__ float xla_tanh_f32(float x) {
  float ax = fabsf(x);
  float xc = fminf(fmaxf(x, -7.90531110763549805f), 7.90531110763549805f);
  float x2 = __fmul_rn(xc, xc);
  float p = -2.76076847742355e-16f;
  p = __fadd_rn(__fmul_rn(x2, p), 2.00018790482477e-13f);
  p = __fadd_rn(__fmul_rn(x2, p), -8.60467152213735e-11f);
  p = __fadd_rn(__fmul_rn(x2, p), 5.12229709037114e-08f);
  p = __fadd_rn(__fmul_rn(x2, p), 1.48572235717979e-05f);
  p = __fadd_rn(__fmul_rn(x2, p), 6.37261928875436e-04f);
  p = __fadd_rn(__fmul_rn(x2, p), 4.89352455891786e-03f);
  float num = __fmul_rn(xc, p);
  float q = 1.19825839466702e-06f;
  q = __fadd_rn(__fmul_rn(x2, q), 1.18534705686654e-04f);
  q = __fadd_rn(__fmul_rn(x2, q), 2.26843463243900e-03f);
  q = __fadd_rn(__fmul_rn(x2, q), 4.89352518554385e-03f);
  float r = __fdiv_rn(num, q);
  return (ax < 0.0004f) ? x : r;
}
__device__ __forceinline__ float sigmoid_ref(float x) {
  return __fadd_rn(0.5f, __fmul_rn(0.5f, xla_tanh_f32(__fmul_rn(0.5f, x))));
}

struct ClsPtrs { const float* p[NLEV]; };
struct LevelPtrs { const float* reg[NLEV]; const float* anc[NLEV]; };

__device__ __forceinline__ void chunk_map(int bid, int& b, int& level, int& chunk) {
  b = bid / NCHUNK_IMG;
  int cid = bid % NCHUNK_IMG;
  if      (cid < 36) { level = 0; chunk = cid; }
  else if (cid < 45) { level = 1; chunk = cid - 36; }
  else if (cid < 48) { level = 2; chunk = cid - 45; }
  else if (cid < 49) { level = 3; chunk = cid - 48; }
  else               { level = 4; chunk = cid - 49; }
}

// ---- K1: parallel logit-prefilter; append (sigmoid bits, ~idx) keys to global buffer ----
__global__ __launch_bounds__(256)
void k_filter(ClsPtrs cp, u32* __restrict__ selcnt, u64* __restrict__ sel) {
  int b, level, chunk;
  chunk_map(blockIdx.x, b, level, chunk);
  int Nloc = c_Nloc[level], lg2 = c_lg2[level];
  int Nsc = Nloc * NCH;
  int g = b * NLEV + level;
  const float* cls = cp.p[level] + (size_t)b * Nsc;
  float tau = c_tau[level];
  int base = chunk * CHUNK;
  int end = base + CHUNK; if (end > Nsc) end = Nsc;
  int lane = threadIdx.x & 63;
  u64 lowm = (1ull << lane) - 1ull;
  for (int i = base + threadIdx.x; i < end; i += 256) {
    float x = cls[i];
    bool selp = x > tau;                 // monotone sigmoid => logit-space superset filter
    u64 mk = __ballot((int)selp);
    if (selp) {
      int ldr = __builtin_ctzll(mk);
      u32 pos0 = 0;
      if (lane == ldr) pos0 = atomicAdd(&selcnt[g], (u32)__popcll(mk));
      pos0 = (u32)__shfl((int)pos0, ldr);
      u32 pos = pos0 + (u32)__popcll(mk & lowm);
      if (pos < CAP) {
        u32 bits = __float_as_uint(sigmoid_ref(x));
        int ch = i >> lg2;
        int loc = i & (Nloc - 1);
        u32 e = (u32)(loc * NCH + ch);   // flat score index ((y*f+x)*9+a)*8+c
        sel[(size_t)g * CAP + pos] = ((u64)bits << 32) | (u32)(~e);
      }
    }
  }
}

// ---- K2: exact top-1000 by rank; guarded fast path + full histogram fallback ----
__global__ __launch_bounds__(1024)
void k_rank(ClsPtrs cp, const u32* __restrict__ selcnt, const u64* __restrict__ sel,
            float* __restrict__ cand_s, u32* __restrict__ cand_t) {
  __shared__ union { u32 hist[NBINS]; u64 keys[CAP]; } sh;  // 64 KB
  __shared__ u32 part[1024];
  __shared__ u32 s_last;
  __shared__ u32 s_cnt;
  __shared__ int s_cut;
  int g = blockIdx.x;
  int b = g / NLEV, l = g % NLEV;
  int Nloc = c_Nloc[l], lg2 = c_lg2[l];
  int Nsc = Nloc * NCH;
  int tid = threadIdx.x;
  int lane = tid & 63;
  u64 lowm = (1ull << lane) - 1ull;
  int obase = b * NCAND + l * TOPK;
  u32 cnt = selcnt[g];
  bool fast = (cnt >= TOPK) && (cnt <= CAP);
  if (fast) {
    u32 m = cnt;
    for (u32 i = tid; i < m; i += 1024) sh.keys[i] = sel[(size_t)g * CAP + i];
    if (tid == 0) s_last = 0;
    __syncthreads();
    for (u32 i = tid; i < m; i += 1024) {
      u64 k0 = sh.keys[i];
      u32 r = 0;
      for (u32 j = 0; j < m; ++j) r += (sh.keys[j] > k0) ? 1u : 0u;
      if (r < TOPK) {
        cand_s[obase + r] = __uint_as_float((u32)(k0 >> 32));
        u32 e = ~((u32)k0);
        cand_t[obase + r] = ((u32)l << 19) | (e & 0x7FFFFu);
        if (r == TOPK - 1) s_last = (u32)(k0 >> 32);
      }
    }
    __syncthreads();
    // guard: rank-999 must beat the filter boundary by >64 ulps (covers any
    // ulp-level non-monotonicity of the tanh poly); else exactness not proven.
    u32 bits_tau = __float_as_uint(sigmoid_ref(c_tau[l]));
    if ((int)cnt != Nsc && !(s_last > bits_tau + 64u)) fast = false;  // block-uniform
  }
  if (fast) return;

  // ---- fallback (never taken for this input; exact for any input) ----
  const float* cls = cp.p[l] + (size_t)b * Nsc;
  for (int i = tid; i < NBINS; i += 1024) sh.hist[i] = 0;
  if (tid == 0) s_cnt = 0;
  __syncthreads();
  for (int i = tid; i < Nsc; i += 1024) {
    float s = sigmoid_ref(cls[i]);
    atomicAdd(&sh.hist[__float_as_uint(s) >> 16], 1u);
  }
  __syncthreads();
  { u32 a = 0; for (int j = 0; j < 16; ++j) a += sh.hist[tid * 16 + j]; part[tid] = a; }
  __syncthreads();
  if (tid == 0) {
    u32 cum = 0; int cut = 0;
    for (int ch = 1023; ch >= 0; --ch) {
      if (cum + part[ch] >= TOPK) {
        u32 cc = cum;
        for (int bin = ch * 16 + 15;; --bin) { cc += sh.hist[bin]; if (cc >= TOPK) { cut = bin; break; } }
        break;
      }
      cum += part[ch];
    }
    s_cut = cut;
  }
  __syncthreads();
  int cut = s_cut;
  __syncthreads();                 // hist reads done before keys overwrite
  for (int i = tid; i < Nsc; i += 1024) {
    float s = sigmoid_ref(cls[i]);
    u32 bits = __float_as_uint(s);
    bool selp = (int)(bits >> 16) >= cut;
    u64 mk = __ballot((int)selp);
    if (selp) {
      int ldr = __builtin_ctzll(mk);
      u32 pos0 = 0;
      if (lane == ldr) pos0 = atomicAdd(&s_cnt, (u32)__popcll(mk));
      pos0 = (u32)__shfl((int)pos0, ldr);
      u32 pos = pos0 + (u32)__popcll(mk & lowm);
      if (pos < CAP) {
        int ch = i >> lg2;
        int loc = i & (Nloc - 1);
        u32 e = (u32)(loc * NCH + ch);
        sh.keys[pos] = ((u64)bits << 32) | (u32)(~e);
      }
    }
  }
  __syncthreads();
  u32 m2 = s_cnt; if (m2 > CAP) m2 = CAP;
  for (u32 i = tid; i < m2; i += 1024) {
    u64 k0 = sh.keys[i];
    u32 r = 0;
    for (u32 j = 0; j < m2; ++j) r += (sh.keys[j] > k0) ? 1u : 0u;
    if (r < TOPK) {
      cand_s[obase + r] = __uint_as_float((u32)(k0 >> 32));
      u32 e = ~((u32)k0);
      cand_t[obase + r] = ((u32)l << 19) | (e & 0x7FFFFu);
    }
  }
  for (u32 r = m2 + tid; r < TOPK; r += 1024) {
    cand_s[obase + r] = -1.0f;
    cand_t[obase + r] = ((u32)l << 19) | r;
  }
}

// IoU > thresh predicate — identical _rn sequence as reference; div only when inter>0
__device__ __forceinline__ bool iou_gt4(float4 p, float pa, float4 q, float qa) {
  float ltx = fmaxf(p.x, q.x), lty = fmaxf(p.y, q.y);
  float rx  = fminf(p.z, q.z), ry  = fminf(p.w, q.w);
  float ww = fmaxf(__fsub_rn(rx, ltx), 0.0f);
  float hh = fmaxf(__fsub_rn(ry, lty), 0.0f);
  float inter = __fmul_rn(ww, hh);
  bool res = false;
  if (inter > 0.0f) {
    float denom = fmaxf(__fsub_rn(__fadd_rn(pa, qa), inter), 1e-7f);
    res = __fdiv_rn(inter, denom) > NMS_TH;
  }
  return res;
}

// ---- K3: fused per-image merge+decode (all waves) then greedy NMS (wave 0) + output ----
__global__ __launch_bounds__(1024)
void k_detect(const float* __restrict__ cand_s, const u32* __restrict__ cand_t,
              LevelPtrs lp,
              float* __restrict__ sort_s, float* __restrict__ sbox, float* __restrict__ slbl,
              float* __restrict__ out) {
  __shared__ u64 keys[NCAND];       // 40 KB
  __shared__ float4 kbc[8][NDET];   // per-class kept boxes (offset space)
  __shared__ float  karc[8][NDET];
  __shared__ int    kidx[NDET];
  __shared__ float4 cbox[64];
  __shared__ float  carea[64];
  __shared__ u64    rowsh[64];
  __shared__ u32    kcnt[8];
  int b = blockIdx.x, tid = threadIdx.x;

  // ---- phase 1: 5-way merge by rank + fused decode (1024 threads) ----
  for (int i = tid; i < NCAND; i += 1024) {
    float s = cand_s[b * NCAND + i];
    u32 t = cand_t[b * NCAND + i];
    u32 hi = (s > SCORE_TH) ? __float_as_uint(s) : 0u;  // invalid -> sorts last
    keys[i] = ((u64)hi << 32) | (u32)(~t);
  }
  __syncthreads();
  for (int i = tid; i < NCAND; i += 1024) {
    u64 k0 = keys[i];
    int l = i / TOPK;
    int rank = i - l * TOPK;                 // own list: earlier entries are greater
    for (int L = 0; L < NLEV; ++L) {
      if (L == l) continue;
      const u64* A = keys + L * TOPK;        // desc-sorted (valid prefix), unique
      int lo = 0, hi2 = TOPK;                // count of A[j] > k0
      while (lo < hi2) { int mid = (lo + hi2) >> 1; if (A[mid] > k0) lo = mid + 1; else hi2 = mid; }
      rank += lo;
    }
    u32 t = ~((u32)k0);
    u32 hi = (u32)(k0 >> 32);
    float bx0 = 0.f, bx1 = 0.f, bx2 = 0.f, bx3 = 0.f, lbl = 0.f;
    if (hi) {
      sort_s[b * NCAND + rank] = __uint_as_float(hi);
      int lv = (int)(t >> 19);
      u32 e = t & 0x7FFFFu;
      int c = (int)(e & 7u);
      u32 anc = e >> 3;              // loc*9 + a
      int a = (int)(anc % 9u);
      int loc = (int)(anc / 9u);
      int f = c_f[lv];
      int Nloc = f * f;
      const float* rp = lp.reg[lv];
      const float* ap = lp.anc[lv] + (size_t)anc * 4;
      float r0 = rp[((size_t)b * NREGCH + (a * 4 + 0)) * Nloc + loc];
      float r1 = rp[((size_t)b * NREGCH + (a * 4 + 1)) * Nloc + loc];
      float r2 = rp[((size_t)b * NREGCH + (a * 4 + 2)) * Nloc + loc];
      float r3 = rp[((size_t)b * NREGCH + (a * 4 + 3)) * Nloc + loc];
      float a0 = ap[0], a1 = ap[1], a2 = ap[2], a3 = ap[3];
      float aw = __fsub_rn(a2, a0);
      float ah = __fsub_rn(a3, a1);
      float acx = __fadd_rn(a0, __fmul_rn(0.5f, aw));
      float acy = __fadd_rn(a1, __fmul_rn(0.5f, ah));
      float dw = fminf(r2, BBOX_CLIP_F);
      float dh = fminf(r3, BBOX_CLIP_F);
      float pcx = __fadd_rn(__fmul_rn(r0, aw), acx);
      float pcy = __fadd_rn(__fmul_rn(r1, ah), acy);
      float pw = __fmul_rn(expf(dw), aw);
      float ph = __fmul_rn(expf(dh), ah);
      float hx = __fmul_rn(0.5f, pw);
      float hy = __fmul_rn(0.5f, ph);
      bx0 = fminf(fmaxf(__fsub_rn(pcx, hx), 0.0f), IMGSZ);
      bx1 = fminf(fmaxf(__fsub_rn(pcy, hy), 0.0f), IMGSZ);
      bx2 = fminf(fmaxf(__fadd_rn(pcx, hx), 0.0f), IMGSZ);
      bx3 = fminf(fmaxf(__fadd_rn(pcy, hy), 0.0f), IMGSZ);
      lbl = (float)c;
    } else {
      sort_s[b * NCAND + rank] = -1.0f;
    }
    float4 v; v.x = bx0; v.y = bx1; v.z = bx2; v.w = bx3;
    ((float4*)sbox)[b * NCAND + rank] = v;
    slbl[b * NCAND + rank] = lbl;
  }
  __syncthreads();                  // phase-1 writes visible to wave 0
  if (tid >= 64) return;

  // ---- phase 2: greedy NMS, one wave, per-class kept lists ----
  int lane = tid;
  u64 lowm = (1ull << lane) - 1ull;
  if (lane < 8) kcnt[lane] = 0;
  int n = 0; bool done = false;
  float  s_nx = sort_s[b * NCAND + lane];
  float4 b_nx = ((const float4*)sbox)[b * NCAND + lane];
  float  l_nx = slbl[b * NCAND + lane];
  for (int base = 0; base < NCAND && !done; base += 64) {
    float s = s_nx; float4 v = b_nx; float lblf = l_nx;
    if (base + 64 < NCAND) {                 // prefetch next group
      int ci2 = base + 64 + lane;
      bool ok = ci2 < NCAND;
      s_nx = ok ? sort_s[b * NCAND + ci2] : -1.0f;
      b_nx = ok ? ((const float4*)sbox)[b * NCAND + ci2] : make_float4(0.f, 0.f, 0.f, 0.f);
      l_nx = ok ? slbl[b * NCAND + ci2] : 0.0f;
    }
    bool valid = s > 0.0f;
    int myc = (int)lblf;
    float off = __fmul_rn(lblf, IMGSZ + 1.0f);
    float4 q;
    q.x = __fadd_rn(v.x, off); q.y = __fadd_rn(v.y, off);
    q.z = __fadd_rn(v.z, off); q.w = __fadd_rn(v.w, off);
    float areaq = __fmul_rn(__fsub_rn(q.z, q.x), __fsub_rn(q.w, q.y));
    cbox[lane] = q; carea[lane] = areaq;
    u64 cm_my = 0;
    for (int c = 0; c < 8; ++c) {
      u64 bc = __ballot((int)(valid && myc == c));
      if (myc == c) cm_my = bc;
    }
    // phase A: test vs kept list of MY class only (cross-class IoU provably 0)
    bool sup = false;
    if (valid) {
      int cnt = (int)kcnt[myc];
      const float4* kb = kbc[myc];
      const float*  ka = karc[myc];
      int k = 0;
      for (; k + 4 <= cnt; k += 4) {
        float4 p0 = kb[k], p1 = kb[k+1], p2 = kb[k+2], p3 = kb[k+3];
        float a0 = ka[k], a1 = ka[k+1], a2 = ka[k+2], a3 = ka[k+3];
        sup = sup | iou_gt4(p0, a0, q, areaq) | iou_gt4(p1, a1, q, areaq)
                  | iou_gt4(p2, a2, q, areaq) | iou_gt4(p3, a3, q, areaq);
      }
      for (; k < cnt; ++k) sup = sup | iou_gt4(kb[k], ka[k], q, areaq);
    }
    u64 pending = __ballot((int)(valid && !sup));
    // phase B: intra-group rows over same-class pending j > lane only
    u64 row = 0;
    if ((pending >> lane) & 1ull) {
      u64 mine = pending & cm_my & ~((2ull << lane) - 1ull);
      while (mine) {
        int j = __builtin_ctzll(mine); mine &= mine - 1ull;
        if (iou_gt4(q, areaq, cbox[j], carea[j])) row |= (1ull << j);
      }
    }
    rowsh[lane] = row;
    u64 nz = __ballot((int)(row != 0ull));
    // phase C
    if ((nz & pending) == 0ull) {            // no intra-group suppression: parallel append
      int avail = NDET - n;
      bool isp = ((pending >> lane) & 1ull) != 0;
      int grank = (int)__popcll(pending & lowm);
      u64 keptb = __ballot((int)(isp && grank < avail));
      if (isp && grank < avail) {
        kidx[n + grank] = base + lane;
        int crank = (int)__popcll(keptb & cm_my & lowm);
        int cb = (int)kcnt[myc];
        kbc[myc][cb + crank] = q; karc[myc][cb + crank] = areaq;
        if (crank == 0) kcnt[myc] = (u32)(cb + (int)__popcll(keptb & cm_my));
      }
      n += (int)__popcll(keptb);
      if (n >= NDET) done = true;
    } else {                                 // rare: serial greedy resolution
      u64 rem = pending;
      while (rem) {
        int r = __builtin_ctzll(rem); rem &= rem - 1ull;
        if (lane == r) {
          kidx[n] = base + r;
          int cb = (int)kcnt[myc];
          kbc[myc][cb] = q; karc[myc][cb] = areaq; kcnt[myc] = (u32)(cb + 1);
        }
        ++n;
        if (n == NDET) { done = true; break; }
        if ((nz >> r) & 1ull) rem &= ~rowsh[r];
      }
    }
    if (__any((int)(!valid))) done = true;   // sorted: rest of list invalid
  }
  // ---- output: boxes [B,300,4] ++ scores [B,300] ++ labels [B,300] ----
  for (int k = lane; k < NDET; k += 64) {
    float bx0 = 0.f, bx1 = 0.f, bx2 = 0.f, bx3 = 0.f, sc = 0.f, lb = -1.0f;
    if (k < n) {
      int i = kidx[k];
      float4 v = ((const float4*)sbox)[b * NCAND + i];
      bx0 = v.x; bx1 = v.y; bx2 = v.z; bx3 = v.w;
      sc = sort_s[b * NCAND + i];
      lb = slbl[b * NCAND + i];
    }
    int idx = b * NDET + k;
    out[(size_t)idx * 4 + 0] = bx0;
    out[(size_t)idx * 4 + 1] = bx1;
    out[(size_t)idx * 4 + 2] = bx2;
    out[(size_t)idx * 4 + 3] = bx3;
    out[NB * NDET * 4 + idx] = sc;
    out[NB * NDET * 5 + idx] = lb;
  }
}

extern "C" void kernel_launch(void* const* d_in, const int* in_sizes, int n_in,
                              void* d_out, int out_size, void* d_ws, size_t ws_size,
                              hipStream_t stream) {
  const float* cls[NLEV]; const float* reg[NLEV]; const float* anc[NLEV];
  bool dict_order = (n_in >= 2) && (in_sizes[1] == 4 * NREGCH * 64 * 64);
  for (int l = 0; l < NLEV; ++l) {
    if (dict_order) {
      cls[l] = (const float*)d_in[3 * l + 0];
      reg[l] = (const float*)d_in[3 * l + 1];
      anc[l] = (const float*)d_in[3 * l + 2];
    } else {
      cls[l] = (const float*)d_in[l];
      reg[l] = (const float*)d_in[NLEV + l];
      anc[l] = (const float*)d_in[2 * NLEV + l];
    }
  }

  char* ws = (char*)d_ws;
  size_t off = 0;
  auto alloc = [&](size_t bytes) -> void* {
    void* p = ws + off;
    off = (off + bytes + 255) & ~(size_t)255;
    return p;
  };
  u32*   selcnt = (u32*)  alloc(20 * 4);
  u64*   sel    = (u64*)  alloc(20ULL * CAP * 8);
  float* cand_s = (float*)alloc((size_t)NB * NCAND * 4);
  u32*   cand_t = (u32*)  alloc((size_t)NB * NCAND * 4);
  float* sort_s = (float*)alloc((size_t)NB * NCAND * 4);
  float* sbox   = (float*)alloc((size_t)NB * NCAND * 16);
  float* slbl   = (float*)alloc((size_t)NB * NCAND * 4);
  (void)ws_size; (void)out_size;

  hipMemsetAsync(selcnt, 0, 20 * 4, stream);

  ClsPtrs cp;
  for (int l = 0; l < NLEV; ++l) cp.p[l] = cls[l];
  LevelPtrs lp;
  for (int l = 0; l < NLEV; ++l) { lp.reg[l] = reg[l]; lp.anc[l] = anc[l]; }

  k_filter<<<NB * NCHUNK_IMG, 256, 0, stream>>>(cp, selcnt, sel);
  k_rank<<<NB * NLEV, 1024, 0, stream>>>(cp, selcnt, sel, cand_s, cand_t);
  k_detect<<<NB, 1024, 0, stream>>>(cand_s, cand_t, lp, sort_s, sbox, slbl, (float*)d_out);
}

// Round 9
// 143.824 us; speedup vs baseline: 2.1427x; 2.1427x over previous
//
#include <hip/hip_runtime.h>
#include <stdint.h>
#include <stddef.h>

typedef unsigned int u32;
typedef unsigned long long u64;

#define NB 4
#define NLEV 5
#define NCH 72      // A*C = 9*8
#define NREGCH 36   // A*4
#define TOPK 1000
#define NCAND 5000  // NLEV*TOPK
#define NDET 300
#define NBINS 16384       // fallback hist: sigmoid float bits >> 16
#define CAP 8192          // per-(b,level) filtered-candidate buffer
#define FASTCAP 2048      // fast-path key limit (2 keys/thread @ 1024 thr)
#define CHUNK 8192
#define NCHUNK_IMG 50     // 36+9+3+1+1
#define IMGSZ 512.0f
#define SCORE_TH 0.05f
#define NMS_TH 0.5f
#define BBOX_CLIP_F 4.135166556742356f

__constant__ int c_f[NLEV]    = {64, 32, 16, 8, 4};
__constant__ int c_Nloc[NLEV] = {4096, 1024, 256, 64, 16};
__constant__ int c_lg2[NLEV]  = {12, 10, 8, 6, 4};
// logit prefilter thresholds: ~1400 expected survivors at levels 0-3 (10-sigma
// margins vs both TOPK=1000 and FASTCAP=2048); level 4 unfiltered (1152 total).
__constant__ float c_tau[NLEV] = {2.594f, 2.075f, 1.433f, 0.513f, -1e30f};

// ---- XLA-CPU-style sigmoid: logistic(x) = 0.5 + 0.5*tanh(0.5*x), fast-tanh poly, no FMA ----
__device__ __forceinline__ float xla_tanh_f32(float x) {
  float ax = fabsf(x);
  float xc = fminf(fmaxf(x, -7.90531110763549805f), 7.90531110763549805f);
  float x2 = __fmul_rn(xc, xc);
  float p = -2.76076847742355e-16f;
  p = __fadd_rn(__fmul_rn(x2, p), 2.00018790482477e-13f);
  p = __fadd_rn(__fmul_rn(x2, p), -8.60467152213735e-11f);
  p = __fadd_rn(__fmul_rn(x2, p), 5.12229709037114e-08f);
  p = __fadd_rn(__fmul_rn(x2, p), 1.48572235717979e-05f);
  p = __fadd_rn(__fmul_rn(x2, p), 6.37261928875436e-04f);
  p = __fadd_rn(__fmul_rn(x2, p), 4.89352455891786e-03f);
  float num = __fmul_rn(xc, p);
  float q = 1.19825839466702e-06f;
  q = __fadd_rn(__fmul_rn(x2, q), 1.18534705686654e-04f);
  q = __fadd_rn(__fmul_rn(x2, q), 2.26843463243900e-03f);
  q = __fadd_rn(__fmul_rn(x2, q), 4.89352518554385e-03f);
  float r = __fdiv_rn(num, q);
  return (ax < 0.0004f) ? x : r;
}
__device__ __forceinline__ float sigmoid_ref(float x) {
  return __fadd_rn(0.5f, __fmul_rn(0.5f, xla_tanh_f32(__fmul_rn(0.5f, x))));
}

struct ClsPtrs { const float* p[NLEV]; };
struct LevelPtrs { const float* reg[NLEV]; const float* anc[NLEV]; };

__device__ __forceinline__ void chunk_map(int bid, int& b, int& level, int& chunk) {
  b = bid / NCHUNK_IMG;
  int cid = bid % NCHUNK_IMG;
  if      (cid < 36) { level = 0; chunk = cid; }
  else if (cid < 45) { level = 1; chunk = cid - 36; }
  else if (cid < 48) { level = 2; chunk = cid - 45; }
  else if (cid < 49) { level = 3; chunk = cid - 48; }
  else               { level = 4; chunk = cid - 49; }
}

// ---- K1: logit-prefilter; ONE global atomic per block (two-pass ballot scheme) ----
__global__ __launch_bounds__(256)
void k_filter(ClsPtrs cp, u32* __restrict__ selcnt, u64* __restrict__ sel) {
  int b, level, chunk;
  chunk_map(blockIdx.x, b, level, chunk);
  int Nloc = c_Nloc[level], lg2 = c_lg2[level];
  int Nsc = Nloc * NCH;
  int g = b * NLEV + level;
  const float* cls = cp.p[level] + (size_t)b * Nsc;
  float tau = c_tau[level];
  int base = chunk * CHUNK;
  int end = base + CHUNK; if (end > Nsc) end = Nsc;
  int wid = threadIdx.x >> 6, lane = threadIdx.x & 63;
  u64 lowm = (1ull << lane) - 1ull;
  __shared__ u32 wcnt[4];
  __shared__ u32 s_gbase;
  // pass A: count survivors per wave (ballot recomputed identically in pass B)
  u32 mycnt = 0;
  for (int i = base + threadIdx.x; i < end; i += 256) {
    u64 mk = __ballot((int)(cls[i] > tau));
    mycnt += (u32)__popcll(mk);
  }
  if (lane == 0) wcnt[wid] = mycnt;
  __syncthreads();
  u32 wbase = 0, tot = 0;
  for (int w = 0; w < 4; ++w) { u32 c = wcnt[w]; if (w < wid) wbase += c; tot += c; }
  if (threadIdx.x == 0 && tot) s_gbase = atomicAdd(&selcnt[g], tot);
  __syncthreads();
  if (!tot) return;
  u32 gb = s_gbase;
  // pass B: recompute masks, write survivors at deterministic in-block offsets
  u32 run = 0;
  for (int i = base + threadIdx.x; i < end; i += 256) {
    float x = cls[i];
    bool selp = x > tau;                 // monotone sigmoid => logit-space superset filter
    u64 mk = __ballot((int)selp);
    if (selp) {
      u32 pos = gb + wbase + run + (u32)__popcll(mk & lowm);
      if (pos < CAP) {
        u32 bits = __float_as_uint(sigmoid_ref(x));
        int ch = i >> lg2;
        int loc = i & (Nloc - 1);
        u32 e = (u32)(loc * NCH + ch);   // flat score index ((y*f+x)*9+a)*8+c
        sel[(size_t)g * CAP + pos] = ((u64)bits << 32) | (u32)(~e);
      }
    }
    run += (u32)__popcll(mk);
  }
}

// ---- K2: exact top-1000 by rank; guarded fast path + full histogram fallback ----
__global__ __launch_bounds__(1024)
void k_rank(ClsPtrs cp, const u32* __restrict__ selcnt, const u64* __restrict__ sel,
            float* __restrict__ cand_s, u32* __restrict__ cand_t) {
  __shared__ union { u32 hist[NBINS]; u64 keys[CAP]; } sh;  // 64 KB
  __shared__ u32 part[1024];
  __shared__ u32 s_last;
  __shared__ u32 s_cnt;
  __shared__ int s_cut;
  int g = blockIdx.x;
  int b = g / NLEV, l = g % NLEV;
  int Nloc = c_Nloc[l], lg2 = c_lg2[l];
  int Nsc = Nloc * NCH;
  int tid = threadIdx.x;
  int lane = tid & 63;
  u64 lowm = (1ull << lane) - 1ull;
  int obase = b * NCAND + l * TOPK;
  u32 cnt = selcnt[g];
  bool fast = (cnt >= TOPK) && (cnt <= FASTCAP);
  if (fast) {
    u32 m = cnt;
    for (u32 i = tid; i < m; i += 1024) sh.keys[i] = sel[(size_t)g * CAP + i];
    if (tid == 0) s_last = 0;
    __syncthreads();
    // 2 keys per thread, one unrolled j-pass: LDS-throughput bound, not latency
    u64 k0a = ((u32)tid < m)        ? sh.keys[tid]        : 0ULL;
    u64 k0b = ((u32)tid + 1024 < m) ? sh.keys[tid + 1024] : 0ULL;
    u32 ra = 0, rb = 0;
    #pragma unroll 8
    for (u32 j = 0; j < m; ++j) {
      u64 kj = sh.keys[j];
      ra += (kj > k0a) ? 1u : 0u;
      rb += (kj > k0b) ? 1u : 0u;
    }
    if ((u32)tid < m && ra < TOPK) {
      cand_s[obase + ra] = __uint_as_float((u32)(k0a >> 32));
      u32 e = ~((u32)k0a);
      cand_t[obase + ra] = ((u32)l << 19) | (e & 0x7FFFFu);
      if (ra == TOPK - 1) s_last = (u32)(k0a >> 32);
    }
    if ((u32)tid + 1024 < m && rb < TOPK) {
      cand_s[obase + rb] = __uint_as_float((u32)(k0b >> 32));
      u32 e = ~((u32)k0b);
      cand_t[obase + rb] = ((u32)l << 19) | (e & 0x7FFFFu);
      if (rb == TOPK - 1) s_last = (u32)(k0b >> 32);
    }
    __syncthreads();
    // guard: rank-999 must beat the filter boundary by >64 ulps (covers any
    // ulp-level non-monotonicity of the tanh poly); else exactness not proven.
    u32 bits_tau = __float_as_uint(sigmoid_ref(c_tau[l]));
    if ((int)cnt != Nsc && !(s_last > bits_tau + 64u)) fast = false;  // block-uniform
  }
  if (fast) return;

  // ---- fallback (never taken for this input; exact for any input) ----
  const float* cls = cp.p[l] + (size_t)b * Nsc;
  for (int i = tid; i < NBINS; i += 1024) sh.hist[i] = 0;
  if (tid == 0) s_cnt = 0;
  __syncthreads();
  for (int i = tid; i < Nsc; i += 1024) {
    float s = sigmoid_ref(cls[i]);
    atomicAdd(&sh.hist[__float_as_uint(s) >> 16], 1u);
  }
  __syncthreads();
  { u32 a = 0; for (int j = 0; j < 16; ++j) a += sh.hist[tid * 16 + j]; part[tid] = a; }
  __syncthreads();
  if (tid == 0) {
    u32 cum = 0; int cut = 0;
    for (int ch = 1023; ch >= 0; --ch) {
      if (cum + part[ch] >= TOPK) {
        u32 cc = cum;
        for (int bin = ch * 16 + 15;; --bin) { cc += sh.hist[bin]; if (cc >= TOPK) { cut = bin; break; } }
        break;
      }
      cum += part[ch];
    }
    s_cut = cut;
  }
  __syncthreads();
  int cut = s_cut;
  __syncthreads();                 // hist reads done before keys overwrite
  for (int i = tid; i < Nsc; i += 1024) {
    float s = sigmoid_ref(cls[i]);
    u32 bits = __float_as_uint(s);
    bool selp = (int)(bits >> 16) >= cut;
    u64 mk = __ballot((int)selp);
    if (selp) {
      int ldr = __builtin_ctzll(mk);
      u32 pos0 = 0;
      if (lane == ldr) pos0 = atomicAdd(&s_cnt, (u32)__popcll(mk));
      pos0 = (u32)__shfl((int)pos0, ldr);
      u32 pos = pos0 + (u32)__popcll(mk & lowm);
      if (pos < CAP) {
        int ch = i >> lg2;
        int loc = i & (Nloc - 1);
        u32 e = (u32)(loc * NCH + ch);
        sh.keys[pos] = ((u64)bits << 32) | (u32)(~e);
      }
    }
  }
  __syncthreads();
  u32 m2 = s_cnt; if (m2 > CAP) m2 = CAP;
  for (u32 i = tid; i < m2; i += 1024) {
    u64 k0 = sh.keys[i];
    u32 r = 0;
    #pragma unroll 8
    for (u32 j = 0; j < m2; ++j) r += (sh.keys[j] > k0) ? 1u : 0u;
    if (r < TOPK) {
      cand_s[obase + r] = __uint_as_float((u32)(k0 >> 32));
      u32 e = ~((u32)k0);
      cand_t[obase + r] = ((u32)l << 19) | (e & 0x7FFFFu);
    }
  }
  for (u32 r = m2 + tid; r < TOPK; r += 1024) {
    cand_s[obase + r] = -1.0f;
    cand_t[obase + r] = ((u32)l << 19) | r;
  }
}

// IoU > thresh predicate — identical _rn sequence as reference; div only when inter>0
__device__ __forceinline__ bool iou_gt4(float4 p, float pa, float4 q, float qa) {
  float ltx = fmaxf(p.x, q.x), lty = fmaxf(p.y, q.y);
  float rx  = fminf(p.z, q.z), ry  = fminf(p.w, q.w);
  float ww = fmaxf(__fsub_rn(rx, ltx), 0.0f);
  float hh = fmaxf(__fsub_rn(ry, lty), 0.0f);
  float inter = __fmul_rn(ww, hh);
  bool res = false;
  if (inter > 0.0f) {
    float denom = fmaxf(__fsub_rn(__fadd_rn(pa, qa), inter), 1e-7f);
    res = __fdiv_rn(inter, denom) > NMS_TH;
  }
  return res;
}

// ---- K3: fused per-image merge+decode (all waves) then greedy NMS (wave 0) + output ----
__global__ __launch_bounds__(1024)
void k_detect(const float* __restrict__ cand_s, const u32* __restrict__ cand_t,
              LevelPtrs lp,
              float* __restrict__ sort_s, float* __restrict__ sbox, float* __restrict__ slbl,
              float* __restrict__ out) {
  __shared__ u64 keys[NCAND];       // 40 KB
  __shared__ float4 kbc[8][NDET];   // per-class kept boxes (offset space)
  __shared__ float  karc[8][NDET];
  __shared__ int    kidx[NDET];
  __shared__ float4 cbox[64];
  __shared__ float  carea[64];
  __shared__ u64    rowsh[64];
  __shared__ u32    kcnt[8];
  int b = blockIdx.x, tid = threadIdx.x;

  // ---- phase 1: 5-way merge by rank + fused decode (1024 threads) ----
  for (int i = tid; i < NCAND; i += 1024) {
    float s = cand_s[b * NCAND + i];
    u32 t = cand_t[b * NCAND + i];
    u32 hi = (s > SCORE_TH) ? __float_as_uint(s) : 0u;  // invalid -> sorts last
    keys[i] = ((u64)hi << 32) | (u32)(~t);
  }
  __syncthreads();
  for (int i = tid; i < NCAND; i += 1024) {
    u64 k0 = keys[i];
    int l = i / TOPK;
    int rank = i - l * TOPK;                 // own list: earlier entries are greater
    for (int L = 0; L < NLEV; ++L) {
      if (L == l) continue;
      const u64* A = keys + L * TOPK;        // desc-sorted (valid prefix), unique
      int lo = 0, hi2 = TOPK;                // count of A[j] > k0
      while (lo < hi2) { int mid = (lo + hi2) >> 1; if (A[mid] > k0) lo = mid + 1; else hi2 = mid; }
      rank += lo;
    }
    u32 t = ~((u32)k0);
    u32 hi = (u32)(k0 >> 32);
    float bx0 = 0.f, bx1 = 0.f, bx2 = 0.f, bx3 = 0.f, lbl = 0.f;
    if (hi) {
      sort_s[b * NCAND + rank] = __uint_as_float(hi);
      int lv = (int)(t >> 19);
      u32 e = t & 0x7FFFFu;
      int c = (int)(e & 7u);
      u32 anc = e >> 3;              // loc*9 + a
      int a = (int)(anc % 9u);
      int loc = (int)(anc / 9u);
      int f = c_f[lv];
      int Nloc = f * f;
      const float* rp = lp.reg[lv];
      const float* ap = lp.anc[lv] + (size_t)anc * 4;
      float r0 = rp[((size_t)b * NREGCH + (a * 4 + 0)) * Nloc + loc];
      float r1 = rp[((size_t)b * NREGCH + (a * 4 + 1)) * Nloc + loc];
      float r2 = rp[((size_t)b * NREGCH + (a * 4 + 2)) * Nloc + loc];
      float r3 = rp[((size_t)b * NREGCH + (a * 4 + 3)) * Nloc + loc];
      float a0 = ap[0], a1 = ap[1], a2 = ap[2], a3 = ap[3];
      float aw = __fsub_rn(a2, a0);
      float ah = __fsub_rn(a3, a1);
      float acx = __fadd_rn(a0, __fmul_rn(0.5f, aw));
      float acy = __fadd_rn(a1, __fmul_rn(0.5f, ah));
      float dw = fminf(r2, BBOX_CLIP_F);
      float dh = fminf(r3, BBOX_CLIP_F);
      float pcx = __fadd_rn(__fmul_rn(r0, aw), acx);
      float pcy = __fadd_rn(__fmul_rn(r1, ah), acy);
      float pw = __fmul_rn(expf(dw), aw);
      float ph = __fmul_rn(expf(dh), ah);
      float hx = __fmul_rn(0.5f, pw);
      float hy = __fmul_rn(0.5f, ph);
      bx0 = fminf(fmaxf(__fsub_rn(pcx, hx), 0.0f), IMGSZ);
      bx1 = fminf(fmaxf(__fsub_rn(pcy, hy), 0.0f), IMGSZ);
      bx2 = fminf(fmaxf(__fadd_rn(pcx, hx), 0.0f), IMGSZ);
      bx3 = fminf(fmaxf(__fadd_rn(pcy, hy), 0.0f), IMGSZ);
      lbl = (float)c;
    } else {
      sort_s[b * NCAND + rank] = -1.0f;
    }
    float4 v; v.x = bx0; v.y = bx1; v.z = bx2; v.w = bx3;
    ((float4*)sbox)[b * NCAND + rank] = v;
    slbl[b * NCAND + rank] = lbl;
  }
  __syncthreads();                  // phase-1 writes visible to wave 0
  if (tid >= 64) return;

  // ---- phase 2: greedy NMS, one wave, per-class kept lists ----
  int lane = tid;
  u64 lowm = (1ull << lane) - 1ull;
  if (lane < 8) kcnt[lane] = 0;
  int n = 0; bool done = false;
  float  s_nx = sort_s[b * NCAND + lane];
  float4 b_nx = ((const float4*)sbox)[b * NCAND + lane];
  float  l_nx = slbl[b * NCAND + lane];
  for (int base = 0; base < NCAND && !done; base += 64) {
    float s = s_nx; float4 v = b_nx; float lblf = l_nx;
    if (base + 64 < NCAND) {                 // prefetch next group
      int ci2 = base + 64 + lane;
      bool ok = ci2 < NCAND;
      s_nx = ok ? sort_s[b * NCAND + ci2] : -1.0f;
      b_nx = ok ? ((const float4*)sbox)[b * NCAND + ci2] : make_float4(0.f, 0.f, 0.f, 0.f);
      l_nx = ok ? slbl[b * NCAND + ci2] : 0.0f;
    }
    bool valid = s > 0.0f;
    int myc = (int)lblf;
    float off = __fmul_rn(lblf, IMGSZ + 1.0f);
    float4 q;
    q.x = __fadd_rn(v.x, off); q.y = __fadd_rn(v.y, off);
    q.z = __fadd_rn(v.z, off); q.w = __fadd_rn(v.w, off);
    float areaq = __fmul_rn(__fsub_rn(q.z, q.x), __fsub_rn(q.w, q.y));
    cbox[lane] = q; carea[lane] = areaq;
    u64 cm_my = 0;
    for (int c = 0; c < 8; ++c) {
      u64 bc = __ballot((int)(valid && myc == c));
      if (myc == c) cm_my = bc;
    }
    // phase A: test vs kept list of MY class only (cross-class IoU provably 0)
    bool sup = false;
    if (valid) {
      int cnt = (int)kcnt[myc];
      const float4* kb = kbc[myc];
      const float*  ka = karc[myc];
      int k = 0;
      for (; k + 4 <= cnt; k += 4) {
        float4 p0 = kb[k], p1 = kb[k+1], p2 = kb[k+2], p3 = kb[k+3];
        float a0 = ka[k], a1 = ka[k+1], a2 = ka[k+2], a3 = ka[k+3];
        sup = sup | iou_gt4(p0, a0, q, areaq) | iou_gt4(p1, a1, q, areaq)
                  | iou_gt4(p2, a2, q, areaq) | iou_gt4(p3, a3, q, areaq);
      }
      for (; k < cnt; ++k) sup = sup | iou_gt4(kb[k], ka[k], q, areaq);
    }
    u64 pending = __ballot((int)(valid && !sup));
    // phase B: intra-group rows over same-class pending j > lane only
    u64 row = 0;
    if ((pending >> lane) & 1ull) {
      u64 mine = pending & cm_my & ~((2ull << lane) - 1ull);
      while (mine) {
        int j = __builtin_ctzll(mine); mine &= mine - 1ull;
        if (iou_gt4(q, areaq, cbox[j], carea[j])) row |= (1ull << j);
      }
    }
    rowsh[lane] = row;
    u64 nz = __ballot((int)(row != 0ull));
    // phase C
    if ((nz & pending) == 0ull) {            // no intra-group suppression: parallel append
      int avail = NDET - n;
      bool isp = ((pending >> lane) & 1ull) != 0;
      int grank = (int)__popcll(pending & lowm);
      u64 keptb = __ballot((int)(isp && grank < avail));
      if (isp && grank < avail) {
        kidx[n + grank] = base + lane;
        int crank = (int)__popcll(keptb & cm_my & lowm);
        int cb = (int)kcnt[myc];
        kbc[myc][cb + crank] = q; karc[myc][cb + crank] = areaq;
        if (crank == 0) kcnt[myc] = (u32)(cb + (int)__popcll(keptb & cm_my));
      }
      n += (int)__popcll(keptb);
      if (n >= NDET) done = true;
    } else {                                 // rare: serial greedy resolution
      u64 rem = pending;
      while (rem) {
        int r = __builtin_ctzll(rem); rem &= rem - 1ull;
        if (lane == r) {
          kidx[n] = base + r;
          int cb = (int)kcnt[myc];
          kbc[myc][cb] = q; karc[myc][cb] = areaq; kcnt[myc] = (u32)(cb + 1);
        }
        ++n;
        if (n == NDET) { done = true; break; }
        if ((nz >> r) & 1ull) rem &= ~rowsh[r];
      }
    }
    if (__any((int)(!valid))) done = true;   // sorted: rest of list invalid
  }
  // ---- output: boxes [B,300,4] ++ scores [B,300] ++ labels [B,300] ----
  for (int k = lane; k < NDET; k += 64) {
    float bx0 = 0.f, bx1 = 0.f, bx2 = 0.f, bx3 = 0.f, sc = 0.f, lb = -1.0f;
    if (k < n) {
      int i = kidx[k];
      float4 v = ((const float4*)sbox)[b * NCAND + i];
      bx0 = v.x; bx1 = v.y; bx2 = v.z; bx3 = v.w;
      sc = sort_s[b * NCAND + i];
      lb = slbl[b * NCAND + i];
    }
    int idx = b * NDET + k;
    out[(size_t)idx * 4 + 0] = bx0;
    out[(size_t)idx * 4 + 1] = bx1;
    out[(size_t)idx * 4 + 2] = bx2;
    out[(size_t)idx * 4 + 3] = bx3;
    out[NB * NDET * 4 + idx] = sc;
    out[NB * NDET * 5 + idx] = lb;
  }
}

extern "C" void kernel_launch(void* const* d_in, const int* in_sizes, int n_in,
                              void* d_out, int out_size, void* d_ws, size_t ws_size,
                              hipStream_t stream) {
  const float* cls[NLEV]; const float* reg[NLEV]; const float* anc[NLEV];
  bool dict_order = (n_in >= 2) && (in_sizes[1] == 4 * NREGCH * 64 * 64);
  for (int l = 0; l < NLEV; ++l) {
    if (dict_order) {
      cls[l] = (const float*)d_in[3 * l + 0];
      reg[l] = (const float*)d_in[3 * l + 1];
      anc[l] = (const float*)d_in[3 * l + 2];
    } else {
      cls[l] = (const float*)d_in[l];
      reg[l] = (const float*)d_in[NLEV + l];
      anc[l] = (const float*)d_in[2 * NLEV + l];
    }
  }

  char* ws = (char*)d_ws;
  size_t off = 0;
  auto alloc = [&](size_t bytes) -> void* {
    void* p = ws + off;
    off = (off + bytes + 255) & ~(size_t)255;
    return p;
  };
  u32*   selcnt = (u32*)  alloc(20 * 4);
  u64*   sel    = (u64*)  alloc(20ULL * CAP * 8);
  float* cand_s = (float*)alloc((size_t)NB * NCAND * 4);
  u32*   cand_t = (u32*)  alloc((size_t)NB * NCAND * 4);
  float* sort_s = (float*)alloc((size_t)NB * NCAND * 4);
  float* sbox   = (float*)alloc((size_t)NB * NCAND * 16);
  float* slbl   = (float*)alloc((size_t)NB * NCAND * 4);
  (void)ws_size; (void)out_size;

  hipMemsetAsync(selcnt, 0, 20 * 4, stream);

  ClsPtrs cp;
  for (int l = 0; l < NLEV; ++l) cp.p[l] = cls[l];
  LevelPtrs lp;
  for (int l = 0; l < NLEV; ++l) { lp.reg[l] = reg[l]; lp.anc[l] = anc[l]; }

  k_filter<<<NB * NCHUNK_IMG, 256, 0, stream>>>(cp, selcnt, sel);
  k_rank<<<NB * NLEV, 1024, 0, stream>>>(cp, selcnt, sel, cand_s, cand_t);
  k_detect<<<NB, 1024, 0, stream>>>(cand_s, cand_t, lp, sort_s, sbox, slbl, (float*)d_out);
}

// Round 10
// 143.287 us; speedup vs baseline: 2.1508x; 1.0037x over previous
//
#include <hip/hip_runtime.h>
#include <stdint.h>
#include <stddef.h>

typedef unsigned int u32;
typedef unsigned long long u64;

#define NB 4
#define NLEV 5
#define NCH 72      // A*C = 9*8
#define NREGCH 36   // A*4
#define TOPK 1000
#define NCAND 5000  // NLEV*TOPK
#define NDET 300
#define NBINS 16384       // fallback hist: sigmoid float bits >> 16
#define CAP 8192          // per-(b,level) filtered-candidate buffer
#define FASTCAP 2048      // fast-path key limit (2 keys/thread @ 1024 thr)
#define CHUNK 8192
#define NCHUNK_IMG 50     // 36+9+3+1+1
#define IMGSZ 512.0f
#define SCORE_TH 0.05f
#define NMS_TH 0.5f
#define BBOX_CLIP_F 4.135166556742356f

__constant__ int c_f[NLEV]    = {64, 32, 16, 8, 4};
__constant__ int c_Nloc[NLEV] = {4096, 1024, 256, 64, 16};
__constant__ int c_lg2[NLEV]  = {12, 10, 8, 6, 4};
// logit prefilter thresholds: ~1400 expected survivors at levels 0-3 (10-sigma
// margins vs both TOPK=1000 and FASTCAP=2048); level 4 unfiltered (1152 total).
__constant__ float c_tau[NLEV] = {2.594f, 2.075f, 1.433f, 0.513f, -1e30f};

// ---- XLA-CPU-style sigmoid: logistic(x) = 0.5 + 0.5*tanh(0.5*x), fast-tanh poly, no FMA ----
__device__ __forceinline__ float xla_tanh_f32(float x) {
  float ax = fabsf(x);
  float xc = fminf(fmaxf(x, -7.90531110763549805f), 7.90531110763549805f);
  float x2 = __fmul_rn(xc, xc);
  float p = -2.76076847742355e-16f;
  p = __fadd_rn(__fmul_rn(x2, p), 2.00018790482477e-13f);
  p = __fadd_rn(__fmul_rn(x2, p), -8.60467152213735e-11f);
  p = __fadd_rn(__fmul_rn(x2, p), 5.12229709037114e-08f);
  p = __fadd_rn(__fmul_rn(x2, p), 1.48572235717979e-05f);
  p = __fadd_rn(__fmul_rn(x2, p), 6.37261928875436e-04f);
  p = __fadd_rn(__fmul_rn(x2, p), 4.89352455891786e-03f);
  float num = __fmul_rn(xc, p);
  float q = 1.19825839466702e-06f;
  q = __fadd_rn(__fmul_rn(x2, q), 1.18534705686654e-04f);
  q = __fadd_rn(__fmul_rn(x2, q), 2.26843463243900e-03f);
  q = __fadd_rn(__fmul_rn(x2, q), 4.89352518554385e-03f);
  float r = __fdiv_rn(num, q);
  return (ax < 0.0004f) ? x : r;
}
__device__ __forceinline__ float sigmoid_ref(float x) {
  return __fadd_rn(0.5f, __fmul_rn(0.5f, xla_tanh_f32(__fmul_rn(0.5f, x))));
}

struct ClsPtrs { const float* p[NLEV]; };
struct LevelPtrs { const float* reg[NLEV]; const float* anc[NLEV]; };

__device__ __forceinline__ void chunk_map(int bid, int& b, int& level, int& chunk) {
  b = bid / NCHUNK_IMG;
  int cid = bid % NCHUNK_IMG;
  if      (cid < 36) { level = 0; chunk = cid; }
  else if (cid < 45) { level = 1; chunk = cid - 36; }
  else if (cid < 48) { level = 2; chunk = cid - 45; }
  else if (cid < 49) { level = 3; chunk = cid - 48; }
  else               { level = 4; chunk = cid - 49; }
}

// ---- K1: logit-prefilter; ONE global atomic per block (two-pass ballot scheme) ----
__global__ __launch_bounds__(256)
void k_filter(ClsPtrs cp, u32* __restrict__ selcnt, u64* __restrict__ sel) {
  int b, level, chunk;
  chunk_map(blockIdx.x, b, level, chunk);
  int Nloc = c_Nloc[level], lg2 = c_lg2[level];
  int Nsc = Nloc * NCH;
  int g = b * NLEV + level;
  const float* cls = cp.p[level] + (size_t)b * Nsc;
  float tau = c_tau[level];
  int base = chunk * CHUNK;
  int end = base + CHUNK; if (end > Nsc) end = Nsc;
  int wid = threadIdx.x >> 6, lane = threadIdx.x & 63;
  u64 lowm = (1ull << lane) - 1ull;
  __shared__ u32 wcnt[4];
  __shared__ u32 s_gbase;
  u32 mycnt = 0;
  for (int i = base + threadIdx.x; i < end; i += 256) {
    u64 mk = __ballot((int)(cls[i] > tau));
    mycnt += (u32)__popcll(mk);
  }
  if (lane == 0) wcnt[wid] = mycnt;
  __syncthreads();
  u32 wbase = 0, tot = 0;
  for (int w = 0; w < 4; ++w) { u32 c = wcnt[w]; if (w < wid) wbase += c; tot += c; }
  if (threadIdx.x == 0 && tot) s_gbase = atomicAdd(&selcnt[g], tot);
  __syncthreads();
  if (!tot) return;
  u32 gb = s_gbase;
  u32 run = 0;
  for (int i = base + threadIdx.x; i < end; i += 256) {
    float x = cls[i];
    bool selp = x > tau;                 // monotone sigmoid => logit-space superset filter
    u64 mk = __ballot((int)selp);
    if (selp) {
      u32 pos = gb + wbase + run + (u32)__popcll(mk & lowm);
      if (pos < CAP) {
        u32 bits = __float_as_uint(sigmoid_ref(x));
        int ch = i >> lg2;
        int loc = i & (Nloc - 1);
        u32 e = (u32)(loc * NCH + ch);   // flat score index ((y*f+x)*9+a)*8+c
        sel[(size_t)g * CAP + pos] = ((u64)bits << 32) | (u32)(~e);
      }
    }
    run += (u32)__popcll(mk);
  }
}

// ---- K2: exact top-1000 by rank; guarded fast path + full histogram fallback ----
__global__ __launch_bounds__(1024)
void k_rank(ClsPtrs cp, const u32* __restrict__ selcnt, const u64* __restrict__ sel,
            float* __restrict__ cand_s, u32* __restrict__ cand_t) {
  __shared__ union { u32 hist[NBINS]; u64 keys[CAP]; } sh;  // 64 KB
  __shared__ u32 part[1024];
  __shared__ u32 s_last;
  __shared__ u32 s_cnt;
  __shared__ int s_cut;
  int g = blockIdx.x;
  int b = g / NLEV, l = g % NLEV;
  int Nloc = c_Nloc[l], lg2 = c_lg2[l];
  int Nsc = Nloc * NCH;
  int tid = threadIdx.x;
  int lane = tid & 63;
  u64 lowm = (1ull << lane) - 1ull;
  int obase = b * NCAND + l * TOPK;
  u32 cnt = selcnt[g];
  bool fast = (cnt >= TOPK) && (cnt <= FASTCAP);
  if (fast) {
    u32 m = cnt;
    for (u32 i = tid; i < m; i += 1024) sh.keys[i] = sel[(size_t)g * CAP + i];
    if (tid == 0) s_last = 0;
    __syncthreads();
    u64 k0a = ((u32)tid < m)        ? sh.keys[tid]        : 0ULL;
    u64 k0b = ((u32)tid + 1024 < m) ? sh.keys[tid + 1024] : 0ULL;
    u32 ra = 0, rb = 0;
    #pragma unroll 8
    for (u32 j = 0; j < m; ++j) {
      u64 kj = sh.keys[j];
      ra += (kj > k0a) ? 1u : 0u;
      rb += (kj > k0b) ? 1u : 0u;
    }
    if ((u32)tid < m && ra < TOPK) {
      cand_s[obase + ra] = __uint_as_float((u32)(k0a >> 32));
      u32 e = ~((u32)k0a);
      cand_t[obase + ra] = ((u32)l << 19) | (e & 0x7FFFFu);
      if (ra == TOPK - 1) s_last = (u32)(k0a >> 32);
    }
    if ((u32)tid + 1024 < m && rb < TOPK) {
      cand_s[obase + rb] = __uint_as_float((u32)(k0b >> 32));
      u32 e = ~((u32)k0b);
      cand_t[obase + rb] = ((u32)l << 19) | (e & 0x7FFFFu);
      if (rb == TOPK - 1) s_last = (u32)(k0b >> 32);
    }
    __syncthreads();
    u32 bits_tau = __float_as_uint(sigmoid_ref(c_tau[l]));
    if ((int)cnt != Nsc && !(s_last > bits_tau + 64u)) fast = false;  // block-uniform
  }
  if (fast) return;

  // ---- fallback (never taken for this input; exact for any input) ----
  const float* cls = cp.p[l] + (size_t)b * Nsc;
  for (int i = tid; i < NBINS; i += 1024) sh.hist[i] = 0;
  if (tid == 0) s_cnt = 0;
  __syncthreads();
  for (int i = tid; i < Nsc; i += 1024) {
    float s = sigmoid_ref(cls[i]);
    atomicAdd(&sh.hist[__float_as_uint(s) >> 16], 1u);
  }
  __syncthreads();
  { u32 a = 0; for (int j = 0; j < 16; ++j) a += sh.hist[tid * 16 + j]; part[tid] = a; }
  __syncthreads();
  if (tid == 0) {
    u32 cum = 0; int cut = 0;
    for (int ch = 1023; ch >= 0; --ch) {
      if (cum + part[ch] >= TOPK) {
        u32 cc = cum;
        for (int bin = ch * 16 + 15;; --bin) { cc += sh.hist[bin]; if (cc >= TOPK) { cut = bin; break; } }
        break;
      }
      cum += part[ch];
    }
    s_cut = cut;
  }
  __syncthreads();
  int cut = s_cut;
  __syncthreads();
  for (int i = tid; i < Nsc; i += 1024) {
    float s = sigmoid_ref(cls[i]);
    u32 bits = __float_as_uint(s);
    bool selp = (int)(bits >> 16) >= cut;
    u64 mk = __ballot((int)selp);
    if (selp) {
      int ldr = __builtin_ctzll(mk);
      u32 pos0 = 0;
      if (lane == ldr) pos0 = atomicAdd(&s_cnt, (u32)__popcll(mk));
      pos0 = (u32)__shfl((int)pos0, ldr);
      u32 pos = pos0 + (u32)__popcll(mk & lowm);
      if (pos < CAP) {
        int ch = i >> lg2;
        int loc = i & (Nloc - 1);
        u32 e = (u32)(loc * NCH + ch);
        sh.keys[pos] = ((u64)bits << 32) | (u32)(~e);
      }
    }
  }
  __syncthreads();
  u32 m2 = s_cnt; if (m2 > CAP) m2 = CAP;
  for (u32 i = tid; i < m2; i += 1024) {
    u64 k0 = sh.keys[i];
    u32 r = 0;
    #pragma unroll 8
    for (u32 j = 0; j < m2; ++j) r += (sh.keys[j] > k0) ? 1u : 0u;
    if (r < TOPK) {
      cand_s[obase + r] = __uint_as_float((u32)(k0 >> 32));
      u32 e = ~((u32)k0);
      cand_t[obase + r] = ((u32)l << 19) | (e & 0x7FFFFu);
    }
  }
  for (u32 r = m2 + tid; r < TOPK; r += 1024) {
    cand_s[obase + r] = -1.0f;
    cand_t[obase + r] = ((u32)l << 19) | r;
  }
}

// ---- K3: decode boxes for selected candidates (gathers spread across 80 CUs) ----
__global__ __launch_bounds__(256)
void k_decode(const float* __restrict__ cand_s, const u32* __restrict__ cand_t,
              LevelPtrs lp, float4* __restrict__ cand_box) {
  int b = blockIdx.y;
  int i = blockIdx.x * 256 + threadIdx.x;
  if (i >= NCAND) return;
  float s = cand_s[b * NCAND + i];
  float4 v = make_float4(0.f, 0.f, 0.f, 0.f);
  if (s > SCORE_TH) {
    u32 t = cand_t[b * NCAND + i];
    int lv = (int)(t >> 19);
    u32 e = t & 0x7FFFFu;
    u32 anc = e >> 3;              // loc*9 + a
    int a = (int)(anc % 9u);
    int loc = (int)(anc / 9u);
    int f = c_f[lv];
    int Nloc = f * f;
    const float* rp = lp.reg[lv];
    const float* ap = lp.anc[lv] + (size_t)anc * 4;
    float r0 = rp[((size_t)b * NREGCH + (a * 4 + 0)) * Nloc + loc];
    float r1 = rp[((size_t)b * NREGCH + (a * 4 + 1)) * Nloc + loc];
    float r2 = rp[((size_t)b * NREGCH + (a * 4 + 2)) * Nloc + loc];
    float r3 = rp[((size_t)b * NREGCH + (a * 4 + 3)) * Nloc + loc];
    float a0 = ap[0], a1 = ap[1], a2 = ap[2], a3 = ap[3];
    float aw = __fsub_rn(a2, a0);
    float ah = __fsub_rn(a3, a1);
    float acx = __fadd_rn(a0, __fmul_rn(0.5f, aw));
    float acy = __fadd_rn(a1, __fmul_rn(0.5f, ah));
    float dw = fminf(r2, BBOX_CLIP_F);
    float dh = fminf(r3, BBOX_CLIP_F);
    float pcx = __fadd_rn(__fmul_rn(r0, aw), acx);
    float pcy = __fadd_rn(__fmul_rn(r1, ah), acy);
    float pw = __fmul_rn(expf(dw), aw);
    float ph = __fmul_rn(expf(dh), ah);
    float hx = __fmul_rn(0.5f, pw);
    float hy = __fmul_rn(0.5f, ph);
    v.x = fminf(fmaxf(__fsub_rn(pcx, hx), 0.0f), IMGSZ);
    v.y = fminf(fmaxf(__fsub_rn(pcy, hy), 0.0f), IMGSZ);
    v.z = fminf(fmaxf(__fadd_rn(pcx, hx), 0.0f), IMGSZ);
    v.w = fminf(fmaxf(__fadd_rn(pcy, hy), 0.0f), IMGSZ);
  }
  cand_box[b * NCAND + i] = v;
}

// IoU > thresh predicate — identical _rn sequence as reference; div only when inter>0
__device__ __forceinline__ bool iou_gt4(float4 p, float pa, float4 q, float qa) {
  float ltx = fmaxf(p.x, q.x), lty = fmaxf(p.y, q.y);
  float rx  = fminf(p.z, q.z), ry  = fminf(p.w, q.w);
  float ww = fmaxf(__fsub_rn(rx, ltx), 0.0f);
  float hh = fmaxf(__fsub_rn(ry, lty), 0.0f);
  float inter = __fmul_rn(ww, hh);
  bool res = false;
  if (inter > 0.0f) {
    float denom = fmaxf(__fsub_rn(__fadd_rn(pa, qa), inter), 1e-7f);
    res = __fdiv_rn(inter, denom) > NMS_TH;
  }
  return res;
}

// ---- K4: per-image merge (rank+permute into LDS) then multi-wave greedy NMS ----
__global__ __launch_bounds__(1024)
void k_detect(const float* __restrict__ cand_s, const u32* __restrict__ cand_t,
              const float4* __restrict__ cand_box, float* __restrict__ out) {
  __shared__ union {
    u64 keys[NCAND];                                           // 40000 B (phase 1)
    struct { float4 kbc[8][NDET]; float karc[8][NDET]; int kidx[NDET]; } nms; // 49200 B
  } u;
  __shared__ float4 sboxL[NCAND];   // 80000 B  (original boxes, sorted order)
  __shared__ float  sscL[NCAND];    // 20000 B
  __shared__ unsigned char slblU[NCAND]; // 5000 B
  __shared__ float4 cbox[64];
  __shared__ float  carea[64];
  __shared__ u64    rowsh[64];
  __shared__ u64    supsh[8];
  __shared__ u32    kcnt[8];
  __shared__ u32    s_done;
  int b = blockIdx.x, tid = threadIdx.x;

  // ---- phase 1: build keys, rank by binary search, permute into LDS ----
  for (int i = tid; i < NCAND; i += 1024) {
    float s = cand_s[b * NCAND + i];
    u32 t = cand_t[b * NCAND + i];
    u32 hi = (s > SCORE_TH) ? __float_as_uint(s) : 0u;  // invalid -> sorts last
    u.keys[i] = ((u64)hi << 32) | (u32)(~t);
  }
  __syncthreads();
  for (int i = tid; i < NCAND; i += 1024) {
    u64 k0 = u.keys[i];
    int l = i / TOPK;
    int rank = i - l * TOPK;                 // own list: earlier entries are greater
    for (int L = 0; L < NLEV; ++L) {
      if (L == l) continue;
      const u64* A = u.keys + L * TOPK;      // desc-sorted (valid prefix), unique
      int lo = 0, hi2 = TOPK;                // count of A[j] > k0
      while (lo < hi2) { int mid = (lo + hi2) >> 1; if (A[mid] > k0) lo = mid + 1; else hi2 = mid; }
      rank += lo;
    }
    u32 hi = (u32)(k0 >> 32);
    u32 t = ~((u32)k0);
    sboxL[rank] = cand_box[b * NCAND + i];
    if (hi) {
      sscL[rank] = __uint_as_float(hi);
      slblU[rank] = (unsigned char)(t & 7u);
    } else {
      sscL[rank] = -1.0f;
      slblU[rank] = 0;
    }
  }
  if (tid < 8) kcnt[tid] = 0;
  if (tid == 0) s_done = 0;
  __syncthreads();                  // phase-1 LDS visible to all waves

  // ---- phase 2: greedy NMS; waves 0-7 split phase A, wave 0 resolves ----
  int wid = tid >> 6, lane = tid & 63;
  u64 lowm = (1ull << lane) - 1ull;
  int n = 0;                        // meaningful in wave 0 only
  for (int base = 0; base < NCAND; base += 64) {
    int ci = base + lane;
    bool inr = ci < NCAND;
    float s = inr ? sscL[ci] : -1.0f;
    bool valid = s > 0.0f;
    int myc = inr ? (int)slblU[ci] : 0;
    float4 v = inr ? sboxL[ci] : make_float4(0.f, 0.f, 0.f, 0.f);
    float off = __fmul_rn((float)myc, IMGSZ + 1.0f);
    float4 q;
    q.x = __fadd_rn(v.x, off); q.y = __fadd_rn(v.y, off);
    q.z = __fadd_rn(v.z, off); q.w = __fadd_rn(v.w, off);
    float areaq = __fmul_rn(__fsub_rn(q.z, q.x), __fsub_rn(q.w, q.y));
    if (wid == 0) { cbox[lane] = q; carea[lane] = areaq; }
    // phase A: waves 0-7 each test stride-8 slice of my class's kept list
    bool sup = false;
    if (wid < 8 && valid) {
      int cnt = (int)kcnt[myc];
      const float4* kb = u.nms.kbc[myc];
      const float*  ka = u.nms.karc[myc];
      for (int k = wid; k < cnt; k += 8)
        sup = sup | iou_gt4(kb[k], ka[k], q, areaq);
    }
    u64 bal = __ballot((int)sup);
    if (wid < 8 && lane == 0) supsh[wid] = bal;
    __syncthreads();
    if (wid == 0) {
      u64 supm = supsh[0] | supsh[1] | supsh[2] | supsh[3]
               | supsh[4] | supsh[5] | supsh[6] | supsh[7];
      u64 validm = __ballot((int)valid);
      u64 pending = validm & ~supm;
      u64 cm_my = 0;
      for (int c = 0; c < 8; ++c) {
        u64 bc = __ballot((int)(valid && myc == c));
        if (myc == c) cm_my = bc;
      }
      // phase B: intra-group rows over same-class pending j > lane
      u64 row = 0;
      if ((pending >> lane) & 1ull) {
        u64 mine = pending & cm_my & ~((2ull << lane) - 1ull);
        while (mine) {
          int j = __builtin_ctzll(mine); mine &= mine - 1ull;
          if (iou_gt4(q, areaq, cbox[j], carea[j])) row |= (1ull << j);
        }
      }
      rowsh[lane] = row;
      u64 nz = __ballot((int)(row != 0ull));
      bool done = false;
      // phase C
      if ((nz & pending) == 0ull) {          // no intra-group suppression: parallel append
        int avail = NDET - n;
        bool isp = ((pending >> lane) & 1ull) != 0;
        int grank = (int)__popcll(pending & lowm);
        u64 keptb = __ballot((int)(isp && grank < avail));
        if (isp && grank < avail) {
          u.nms.kidx[n + grank] = base + lane;
          int crank = (int)__popcll(keptb & cm_my & lowm);
          int cb = (int)kcnt[myc];
          u.nms.kbc[myc][cb + crank] = q; u.nms.karc[myc][cb + crank] = areaq;
          if (crank == 0) kcnt[myc] = (u32)(cb + (int)__popcll(keptb & cm_my));
        }
        n += (int)__popcll(keptb);
        if (n >= NDET) done = true;
      } else {                               // serial greedy resolution
        u64 rem = pending;
        while (rem) {
          int r = __builtin_ctzll(rem); rem &= rem - 1ull;
          if (lane == r) {
            u.nms.kidx[n] = base + r;
            int cb = (int)kcnt[myc];
            u.nms.kbc[myc][cb] = q; u.nms.karc[myc][cb] = areaq; kcnt[myc] = (u32)(cb + 1);
          }
          ++n;
          if (n == NDET) { done = true; break; }
          if ((nz >> r) & 1ull) rem &= ~rowsh[r];
        }
      }
      if (__any((int)(!valid))) done = true; // sorted: rest of list invalid
      if (lane == 0) s_done = done ? 1u : 0u;
    }
    __syncthreads();
    if (s_done) break;                       // uniform across all 16 waves
  }
  // ---- output (wave 0): boxes [B,300,4] ++ scores [B,300] ++ labels [B,300] ----
  if (wid == 0) {
    for (int k = lane; k < NDET; k += 64) {
      float bx0 = 0.f, bx1 = 0.f, bx2 = 0.f, bx3 = 0.f, sc = 0.f, lb = -1.0f;
      if (k < n) {
        int i = u.nms.kidx[k];
        float4 v = sboxL[i];
        bx0 = v.x; bx1 = v.y; bx2 = v.z; bx3 = v.w;
        sc = sscL[i];
        lb = (float)slblU[i];
      }
      int idx = b * NDET + k;
      out[(size_t)idx * 4 + 0] = bx0;
      out[(size_t)idx * 4 + 1] = bx1;
      out[(size_t)idx * 4 + 2] = bx2;
      out[(size_t)idx * 4 + 3] = bx3;
      out[NB * NDET * 4 + idx] = sc;
      out[NB * NDET * 5 + idx] = lb;
    }
  }
}

extern "C" void kernel_launch(void* const* d_in, const int* in_sizes, int n_in,
                              void* d_out, int out_size, void* d_ws, size_t ws_size,
                              hipStream_t stream) {
  const float* cls[NLEV]; const float* reg[NLEV]; const float* anc[NLEV];
  bool dict_order = (n_in >= 2) && (in_sizes[1] == 4 * NREGCH * 64 * 64);
  for (int l = 0; l < NLEV; ++l) {
    if (dict_order) {
      cls[l] = (const float*)d_in[3 * l + 0];
      reg[l] = (const float*)d_in[3 * l + 1];
      anc[l] = (const float*)d_in[3 * l + 2];
    } else {
      cls[l] = (const float*)d_in[l];
      reg[l] = (const float*)d_in[NLEV + l];
      anc[l] = (const float*)d_in[2 * NLEV + l];
    }
  }

  char* ws = (char*)d_ws;
  size_t off = 0;
  auto alloc = [&](size_t bytes) -> void* {
    void* p = ws + off;
    off = (off + bytes + 255) & ~(size_t)255;
    return p;
  };
  u32*    selcnt   = (u32*)   alloc(20 * 4);
  u64*    sel      = (u64*)   alloc(20ULL * CAP * 8);
  float*  cand_s   = (float*) alloc((size_t)NB * NCAND * 4);
  u32*    cand_t   = (u32*)   alloc((size_t)NB * NCAND * 4);
  float4* cand_box = (float4*)alloc((size_t)NB * NCAND * 16);
  (void)ws_size; (void)out_size;

  hipMemsetAsync(selcnt, 0, 20 * 4, stream);

  ClsPtrs cp;
  for (int l = 0; l < NLEV; ++l) cp.p[l] = cls[l];
  LevelPtrs lp;
  for (int l = 0; l < NLEV; ++l) { lp.reg[l] = reg[l]; lp.anc[l] = anc[l]; }

  k_filter<<<NB * NCHUNK_IMG, 256, 0, stream>>>(cp, selcnt, sel);
  k_rank<<<NB * NLEV, 1024, 0, stream>>>(cp, selcnt, sel, cand_s, cand_t);
  k_decode<<<dim3((NCAND + 255) / 256, NB), 256, 0, stream>>>(cand_s, cand_t, lp, cand_box);
  k_detect<<<NB, 1024, 0, stream>>>(cand_s, cand_t, cand_box, (float*)d_out);
}